// Round 7
// baseline (254.398 us; speedup 1.0000x reference)
//
#include <hip/hip_runtime.h>
#include <math.h>

// Problem constants (B=4, T=4096, D=2048, K=4)
#define D_DIM 2048
#define T_DIM 4096
#define EPSI  1e-5f
#define RB    8                 // rows per thread in conv pass

typedef float vfloat4 __attribute__((ext_vector_type(4)));

__device__ __forceinline__ float silu(float v) {
    return v * __builtin_amdgcn_rcpf(1.f + __expf(-v));
}

__device__ __forceinline__ void nt_store4(float* p, float a, float b, float c, float d) {
    vfloat4 v = { a, b, c, d };
    __builtin_nontemporal_store(v, (vfloat4*)p);
}

// R7: two-pass split. R6 proved the plateau is NOT memory-latency (64KB DMA
// permanently in flight still gave 2.5 TB/s): it's the monolithic structure --
// every store behind a block-wide reduce->barrier->broadcast rendezvous.
// The 6.6 TB/s fillBuffer on this chip has no barriers and 9% occupancy.
// So: decouple. Pass A computes inv-RMS per row (wave-per-row, registers
// only, zero LDS/barriers). Pass B is a pure streaming conv (thread = f4-col
// x 8 rows, zero LDS/barriers/shfl); x is L3-resident after pass A so B pays
// mostly the 131 MB write.

// ---- Pass A: one wave per row -> inv[row] ----
__global__ __launch_bounds__(256, 8) void rms_kernel(
    const float* __restrict__ x, float* __restrict__ invs)
{
    const int row  = blockIdx.x * 4 + (threadIdx.x >> 6);
    const int lane = threadIdx.x & 63;
    const float* rp = x + (size_t)row * D_DIM + lane * 4;

    float4 v[8];
#pragma unroll
    for (int j = 0; j < 8; ++j)
        v[j] = *(const float4*)(rp + j * 256);   // 8 independent 16B loads

    float a0 = 0.f, a1 = 0.f, a2 = 0.f, a3 = 0.f;
#pragma unroll
    for (int j = 0; j < 8; ++j) {
        a0 = fmaf(v[j].x, v[j].x, a0);
        a1 = fmaf(v[j].y, v[j].y, a1);
        a2 = fmaf(v[j].z, v[j].z, a2);
        a3 = fmaf(v[j].w, v[j].w, a3);
    }
    float p = (a0 + a1) + (a2 + a3);
#pragma unroll
    for (int off = 32; off > 0; off >>= 1) p += __shfl_down(p, off, 64);
    if (lane == 0)
        invs[row] = rsqrtf(p * (1.0f / D_DIM) + EPSI);
}

// ---- Pass B: thread = one float4 column x RB consecutive rows ----
__global__ __launch_bounds__(512, 4) void conv_kernel(
    const float* __restrict__ x,
    const float* __restrict__ invs,
    const float* __restrict__ g,
    const float* __restrict__ w,
    float* __restrict__ out)
{
    const int col = threadIdx.x;          // f4 column 0..511
    const int grp = blockIdx.x;           // row-group
    const int b   = grp >> 9;             // 512 groups per batch image
    const int t0  = (grp & 511) * RB;
    const int d0  = col * 4;

    const float* xb = x    + (size_t)b * T_DIM * D_DIM + d0;
    const float* ib = invs + (size_t)b * T_DIM;
    float*       ob = out  + (size_t)b * T_DIM * D_DIM + d0;

    const float4 gv = *(const float4*)(g + d0);
    float wgt[4][4];
#pragma unroll
    for (int j = 0; j < 4; ++j) {
        float4 wv = *(const float4*)(w + (size_t)(d0 + j) * 4);
        wgt[j][0] = wv.x; wgt[j][1] = wv.y; wgt[j][2] = wv.z; wgt[j][3] = wv.w;
    }

    // stage RB+3 row elements + inverse-rms scalars (block-uniform branch)
    float4 xv[RB + 3];
    float  iv[RB + 3];
#pragma unroll
    for (int r = 0; r < RB + 3; ++r) {
        const int t = t0 - 3 + r;
        if (t >= 0) {
            xv[r] = *(const float4*)(xb + (size_t)t * D_DIM);
            iv[r] = ib[t];                // uniform address -> scalar load
        } else {
            xv[r] = make_float4(0.f, 0.f, 0.f, 0.f);
            iv[r] = 0.f;
        }
    }
    __builtin_amdgcn_sched_barrier(0);    // keep the load burst ahead of compute

    float win[3][4];
#pragma unroll
    for (int r = 0; r < 3; ++r) {
        win[r][0] = xv[r].x * iv[r] * gv.x;
        win[r][1] = xv[r].y * iv[r] * gv.y;
        win[r][2] = xv[r].z * iv[r] * gv.z;
        win[r][3] = xv[r].w * iv[r] * gv.w;
    }

#pragma unroll
    for (int i = 0; i < RB; ++i) {
        const float4 xc = xv[i + 3];
        const float  ic = iv[i + 3];
        const float y[4] = { xc.x * ic * gv.x, xc.y * ic * gv.y,
                             xc.z * ic * gv.z, xc.w * ic * gv.w };
        float o[4];
#pragma unroll
        for (int j = 0; j < 4; ++j) {
            const float v = wgt[j][0] * win[0][j] + wgt[j][1] * win[1][j] +
                            wgt[j][2] * win[2][j] + wgt[j][3] * y[j];
            o[j] = silu(v);
        }
        nt_store4(ob + (size_t)(t0 + i) * D_DIM, o[0], o[1], o[2], o[3]);
#pragma unroll
        for (int j = 0; j < 4; ++j) {
            win[0][j] = win[1][j]; win[1][j] = win[2][j]; win[2][j] = y[j];
        }
    }
}

extern "C" void kernel_launch(void* const* d_in, const int* in_sizes, int n_in,
                              void* d_out, int out_size, void* d_ws, size_t ws_size,
                              hipStream_t stream) {
    const float* x = (const float*)d_in[0];
    const float* g = (const float*)d_in[1];   // norm_weight [D]
    const float* w = (const float*)d_in[2];   // conv_weight [D,1,K]
    float* out  = (float*)d_out;
    float* invs = (float*)d_ws;               // B*T floats = 64 KB

    const int total = in_sizes[0];            // B*T*D
    const int rows  = total / D_DIM;          // B*T = 16384

    rms_kernel<<<dim3(rows / 4), 256, 0, stream>>>(x, invs);
    conv_kernel<<<dim3(rows / RB), 512, 0, stream>>>(x, invs, g, w, out);
}

// Round 8
// 236.157 us; speedup vs baseline: 1.0772x; 1.0772x over previous
//
#include <hip/hip_runtime.h>
#include <math.h>

// Problem constants (B=4, T=4096, D=2048, K=4)
#define D_DIM 2048
#define T_DIM 4096
#define TT    8                // output rows per block (DMA-staged)
#define NT    512              // threads: block spans full D, float4/thread
#define NW    8                // waves per block
#define ROW_F D_DIM
#define AS1 __attribute__((address_space(1)))
#define AS3 __attribute__((address_space(3)))

typedef float vfloat4 __attribute__((ext_vector_type(4)));

__device__ __forceinline__ float silu(float v) {
    return v * __builtin_amdgcn_rcpf(1.f + __expf(-v));
}

__device__ __forceinline__ void nt_store4(float* p, float a, float b, float c, float d) {
    vfloat4 v = { a, b, c, d };
    __builtin_nontemporal_store(v, (vfloat4*)p);
}

// R8: R5 lineage (champion: one-shot DMA blocks, die-and-relaunch), with
// read-amplification cut 1.75x -> 1.375x:
//   - TT=8: DMA-stage 8 main rows (64 KB LDS, 2 blocks/CU), halo cost
//     amortized over twice the output; 2 barriers per 8 rows (was per 4).
//   - halo rows (3) via register loads + per-wave partial tree (no LDS
//     staging; these rows are L2-hot from the neighbor block's DMA).
//   - wave-per-row LDS reduce: 8 waves <-> 8 rows, no idle waves, one
//     shfl chain per wave, inv published directly.
// R6 falsified the latency theory (64KB perpetually in flight -> still
// 2.5 TB/s HBM); R5's app-level L2 traffic already runs ~5 TB/s, so the
// lever is useful-fraction of that stream, not more bytes in flight.
__global__ __launch_bounds__(NT, 4) void fused_kernel(
    const float* __restrict__ x,
    const float* __restrict__ g,
    const float* __restrict__ w,
    float* __restrict__ out)
{
    const int b    = blockIdx.y;
    const int t0   = blockIdx.x * TT;
    const int tid  = threadIdx.x;
    const int d0   = tid * 4;
    const int lane = tid & 63;
    const int wid  = tid >> 6;

    __shared__ __align__(16) float buf[TT * ROW_F];   // 64 KiB: 8 staged rows
    __shared__ __align__(16) float hpart[3][NW];      // halo partial tree
    __shared__ __align__(16) float inv_s[TT];

    const float* xb = x   + (size_t)b * T_DIM * D_DIM;
    float*       ob = out + (size_t)b * T_DIM * D_DIM + d0;

    // ---- halo rows t0-3..t0-1: register loads (L2-hot) ----
    float4 hv[3];
#pragma unroll
    for (int r = 0; r < 3; ++r) {
        const int t = t0 - 3 + r;    // block-uniform condition
        hv[r] = (t >= 0) ? *(const float4*)(xb + (size_t)t * D_DIM + d0)
                         : make_float4(0.f, 0.f, 0.f, 0.f);
    }

    // ---- DMA all 8 main rows into LDS (fire-and-forget, no dest regs) ----
#pragma unroll
    for (int r = 0; r < TT; ++r) {
        const float* gsrc = xb + (size_t)(t0 + r) * D_DIM + d0;
        float* ldst = buf + r * ROW_F + d0;
        __builtin_amdgcn_global_load_lds((const AS1 void*)gsrc,
                                         (AS3 void*)ldst, 16, 0, 0);
    }

    // ---- params (L1/L2-resident) ----
    const float4 gv = *(const float4*)(g + d0);
    float wgt[4][4];
#pragma unroll
    for (int j = 0; j < 4; ++j) {
        float4 wv = *(const float4*)(w + (size_t)(d0 + j) * 4);
        wgt[j][0] = wv.x; wgt[j][1] = wv.y; wgt[j][2] = wv.z; wgt[j][3] = wv.w;
    }

    // ---- halo partial tree (overlaps the DMA drain) ----
#pragma unroll
    for (int r = 0; r < 3; ++r) {
        float p = hv[r].x*hv[r].x + hv[r].y*hv[r].y
                + hv[r].z*hv[r].z + hv[r].w*hv[r].w;
#pragma unroll
        for (int off = 32; off > 0; off >>= 1) p += __shfl_down(p, off, 64);
        if (lane == 0) hpart[r][wid] = p;
    }

    __syncthreads();   // drains DMA (vmcnt) + hpart writes (lgkm)

    // ---- wave-per-row reduce: wave w sums staged row w ----
    {
        const float* rp = buf + wid * ROW_F;
        float p = 0.f;
#pragma unroll
        for (int j = 0; j < 8; ++j) {
            float4 v = *(const float4*)(rp + (j * 64 + lane) * 4);  // conflict-free
            p = fmaf(v.x, v.x, p); p = fmaf(v.y, v.y, p);
            p = fmaf(v.z, v.z, p); p = fmaf(v.w, v.w, p);
        }
#pragma unroll
        for (int off = 32; off > 0; off >>= 1) p += __shfl_down(p, off, 64);
        if (lane == 0) inv_s[wid] = rsqrtf(p * (1.0f / D_DIM) + 1e-5f);
    }
    __syncthreads();

    // ---- halo inv from partial tree (broadcast LDS reads, per-thread) ----
    float win[3][4];
#pragma unroll
    for (int r = 0; r < 3; ++r) {
        const float* sp = hpart[r];
        const float s = sp[0]+sp[1]+sp[2]+sp[3]+sp[4]+sp[5]+sp[6]+sp[7];
        const float inv = rsqrtf(s * (1.0f / D_DIM) + 1e-5f);
        win[r][0] = hv[r].x * inv * gv.x;
        win[r][1] = hv[r].y * inv * gv.y;
        win[r][2] = hv[r].z * inv * gv.z;
        win[r][3] = hv[r].w * inv * gv.w;
    }

    // ---- normalize + conv + SiLU + store (no further barriers) ----
#pragma unroll
    for (int i = 0; i < TT; ++i) {
        const float inv = inv_s[i];                         // broadcast read
        float4 v = *(const float4*)(buf + i * ROW_F + d0);  // 2-way (free)
        const float y[4] = { v.x * inv * gv.x, v.y * inv * gv.y,
                             v.z * inv * gv.z, v.w * inv * gv.w };
        float o[4];
#pragma unroll
        for (int j = 0; j < 4; ++j) {
            const float t = wgt[j][0] * win[0][j] + wgt[j][1] * win[1][j] +
                            wgt[j][2] * win[2][j] + wgt[j][3] * y[j];
            o[j] = silu(t);
        }
        nt_store4(ob + (size_t)(t0 + i) * D_DIM, o[0], o[1], o[2], o[3]);
#pragma unroll
        for (int j = 0; j < 4; ++j) {
            win[0][j] = win[1][j]; win[1][j] = win[2][j]; win[2][j] = y[j];
        }
    }
}

extern "C" void kernel_launch(void* const* d_in, const int* in_sizes, int n_in,
                              void* d_out, int out_size, void* d_ws, size_t ws_size,
                              hipStream_t stream) {
    const float* x = (const float*)d_in[0];
    const float* g = (const float*)d_in[1];   // norm_weight [D]
    const float* w = (const float*)d_in[2];   // conv_weight [D,1,K]
    float* out = (float*)d_out;

    const int total = in_sizes[0];            // B*T*D
    const int rows  = total / D_DIM;          // B*T
    const int B     = rows / T_DIM;

    dim3 grid(T_DIM / TT, B);                 // 512 x 4 = 2048 blocks
    fused_kernel<<<grid, NT, 0, stream>>>(x, g, w, out);
}